// Round 1
// baseline (662.144 us; speedup 1.0000x reference)
//
#include <hip/hip_runtime.h>
#include <cstddef>

#define INPUT_SIZE 300
#define HIDDEN 128
#define BSZ 256
#define TSZ 512

// ---------------- Phase 1: xp = x @ W_ih^T + (b_ih + b_hh) ----------------
// GEMM: M = B*T = 131072, K = 300, N = 128.  fp32 VALU (no fp32 MFMA on CDNA4).
#define BM 64
#define BN 128
#define BK 16
#define TM 4
#define TN 8

__global__ __launch_bounds__(256) void xp_gemm(
    const float* __restrict__ x, const float* __restrict__ W,
    const float* __restrict__ b_ih, const float* __restrict__ b_hh,
    float* __restrict__ xp) {
  // A staged transposed: As[k][m] so the compute loop reads a float4 of m.
  __shared__ float As[BK][BM + 4];   // 16 x 68
  __shared__ float Bs[BK][BN + 4];   // 16 x 132
  const int tid = threadIdx.x;
  const int m0 = blockIdx.x * BM;
  const int tx = tid & 15;   // 16 groups over N: each covers TN=8 cols
  const int ty = tid >> 4;   // 16 groups over M: each covers TM=4 rows

  float acc[TM][TN];
#pragma unroll
  for (int i = 0; i < TM; ++i)
#pragma unroll
    for (int j = 0; j < TN; ++j) acc[i][j] = 0.0f;

  // A-load mapping: 64x16 tile = 1024 floats; thread -> one float4 along k
  const int a_r = tid >> 2;          // m row 0..63
  const int a_c = (tid & 3) * 4;     // k col {0,4,8,12}

  for (int k0 = 0; k0 < INPUT_SIZE; k0 += BK) {
    // ---- load A tile (transposed into As[k][m]) ----
    {
      const int k = k0 + a_c;
      const float* src = x + (size_t)(m0 + a_r) * INPUT_SIZE + k;
      float4 v;
      if (k + 3 < INPUT_SIZE) {
        v = *(const float4*)src;
      } else {
        v.x = (k + 0 < INPUT_SIZE) ? src[0] : 0.0f;
        v.y = (k + 1 < INPUT_SIZE) ? src[1] : 0.0f;
        v.z = (k + 2 < INPUT_SIZE) ? src[2] : 0.0f;
        v.w = (k + 3 < INPUT_SIZE) ? src[3] : 0.0f;
      }
      As[a_c + 0][a_r] = v.x;
      As[a_c + 1][a_r] = v.y;
      As[a_c + 2][a_r] = v.z;
      As[a_c + 3][a_r] = v.w;
    }
    // ---- load B tile: Bs[k][n] = W[n][k0+k], 2048 floats, 2 float4/thread ----
#pragma unroll
    for (int p = 0; p < 2; ++p) {
      const int idx = tid * 4 + p * 1024;
      const int n = idx >> 4;          // 0..127
      const int c = idx & 15;          // {0,4,8,12}
      const int k = k0 + c;
      const float* src = W + (size_t)n * INPUT_SIZE + k;
      float4 v;
      if (k + 3 < INPUT_SIZE) {
        v = *(const float4*)src;
      } else {
        v.x = (k + 0 < INPUT_SIZE) ? src[0] : 0.0f;
        v.y = (k + 1 < INPUT_SIZE) ? src[1] : 0.0f;
        v.z = (k + 2 < INPUT_SIZE) ? src[2] : 0.0f;
        v.w = (k + 3 < INPUT_SIZE) ? src[3] : 0.0f;
      }
      Bs[c + 0][n] = v.x;
      Bs[c + 1][n] = v.y;
      Bs[c + 2][n] = v.z;
      Bs[c + 3][n] = v.w;
    }
    __syncthreads();

#pragma unroll
    for (int k = 0; k < BK; ++k) {
      const float4 av  = *(const float4*)&As[k][ty * TM];
      const float4 bv0 = *(const float4*)&Bs[k][tx * TN];
      const float4 bv1 = *(const float4*)&Bs[k][tx * TN + 4];
      const float a[TM] = {av.x, av.y, av.z, av.w};
      const float bb[TN] = {bv0.x, bv0.y, bv0.z, bv0.w,
                            bv1.x, bv1.y, bv1.z, bv1.w};
#pragma unroll
      for (int i = 0; i < TM; ++i)
#pragma unroll
        for (int j = 0; j < TN; ++j) acc[i][j] = fmaf(a[i], bb[j], acc[i][j]);
    }
    __syncthreads();
  }

  // epilogue: + (b_ih + b_hh), store xp in [B,T,H] layout (m = b*T + t)
  float bsum[TN];
#pragma unroll
  for (int j = 0; j < TN; ++j)
    bsum[j] = b_ih[tx * TN + j] + b_hh[tx * TN + j];
#pragma unroll
  for (int i = 0; i < TM; ++i) {
    const size_t row = (size_t)(m0 + ty * TM + i) * HIDDEN + tx * TN;
    float4 o0, o1;
    o0.x = acc[i][0] + bsum[0]; o0.y = acc[i][1] + bsum[1];
    o0.z = acc[i][2] + bsum[2]; o0.w = acc[i][3] + bsum[3];
    o1.x = acc[i][4] + bsum[4]; o1.y = acc[i][5] + bsum[5];
    o1.z = acc[i][6] + bsum[6]; o1.w = acc[i][7] + bsum[7];
    *(float4*)(xp + row) = o0;
    *(float4*)(xp + row + 4) = o1;
  }
}

// ---------------- Phase 2: sequential scan over T + fused FC ----------------
// One block per batch row; thread j owns hidden unit j, W_hh row j in VGPRs.
// h lives in LDS (reads are broadcasts). xp staged in 8-step double-buffered
// LDS chunks so HBM latency (~900 cyc) stays off the per-step critical path.
#define CH 8

__global__ __launch_bounds__(128) void rnn_scan(
    const float* __restrict__ xp, const float* __restrict__ Whh,
    const float* __restrict__ fc_w, const float* __restrict__ fc_b,
    float* __restrict__ out) {
  const int b = blockIdx.x;
  const int j = threadIdx.x;
  __shared__ float h[HIDDEN];
  __shared__ float xs[2][CH][HIDDEN];

  // W_hh row j -> registers (128 VGPRs; only 2 waves/block so no occupancy hit)
  float w[HIDDEN];
  const float* wrow = Whh + (size_t)j * HIDDEN;
#pragma unroll
  for (int k4 = 0; k4 < HIDDEN / 4; ++k4) {
    const float4 v = *(const float4*)(wrow + k4 * 4);
    w[4 * k4 + 0] = v.x; w[4 * k4 + 1] = v.y;
    w[4 * k4 + 2] = v.z; w[4 * k4 + 3] = v.w;
  }

  const float* xpb = xp + (size_t)b * TSZ * HIDDEN;
  // preload chunk 0: 8*128 floats = 2 float4/thread
  {
    const float4 v0 = *(const float4*)(xpb + j * 4);
    const float4 v1 = *(const float4*)(xpb + 512 + j * 4);
    const int i0 = j * 4, i1 = j * 4 + 512;
    *(float4*)&xs[0][i0 >> 7][i0 & 127] = v0;
    *(float4*)&xs[0][i1 >> 7][i1 & 127] = v1;
  }
  h[j] = 0.0f;
  __syncthreads();

  int cur = 0;
  for (int c = 0; c < TSZ / CH; ++c) {
    // issue next chunk's global loads before compute; latency hides behind 8 steps
    float4 g0, g1;
    const bool havenext = (c + 1 < TSZ / CH);
    if (havenext) {
      const float* nb = xpb + (size_t)(c + 1) * CH * HIDDEN;
      g0 = *(const float4*)(nb + j * 4);
      g1 = *(const float4*)(nb + 512 + j * 4);
    }
#pragma unroll
    for (int s = 0; s < CH; ++s) {
      float acc = xs[cur][s][j];
#pragma unroll
      for (int k4 = 0; k4 < HIDDEN / 4; ++k4) {
        const float4 hv = *(const float4*)&h[k4 * 4];  // broadcast, conflict-free
        acc = fmaf(hv.x, w[4 * k4 + 0], acc);
        acc = fmaf(hv.y, w[4 * k4 + 1], acc);
        acc = fmaf(hv.z, w[4 * k4 + 2], acc);
        acc = fmaf(hv.w, w[4 * k4 + 3], acc);
      }
      // tanh(x) = sign(x) * (1 - e) / (1 + e), e = exp(-2|x|)  (overflow-safe)
      const float e = __expf(-2.0f * fabsf(acc));
      const float r = __fdividef(1.0f - e, 1.0f + e);
      const float hn = copysignf(r, acc);
      __syncthreads();           // all reads of h done
      h[j] = hn;
      __syncthreads();           // new h visible
    }
    if (havenext) {
      const int nxt = cur ^ 1;
      const int i0 = j * 4, i1 = j * 4 + 512;
      *(float4*)&xs[nxt][i0 >> 7][i0 & 127] = g0;
      *(float4*)&xs[nxt][i1 >> 7][i1 & 127] = g1;
      __syncthreads();
      cur = nxt;
    }
  }

  // fused FC on h_last: out[b][c] = h . fc_w[c] + fc_b[c]
  if (j < 2) {
    float s = fc_b[j];
    const float* fw = fc_w + (size_t)j * HIDDEN;
#pragma unroll 16
    for (int k = 0; k < HIDDEN; ++k) s = fmaf(h[k], fw[k], s);
    out[b * 2 + j] = s;
  }
}

extern "C" void kernel_launch(void* const* d_in, const int* in_sizes, int n_in,
                              void* d_out, int out_size, void* d_ws, size_t ws_size,
                              hipStream_t stream) {
  const float* x    = (const float*)d_in[0];
  const float* W_ih = (const float*)d_in[1];
  const float* W_hh = (const float*)d_in[2];
  const float* b_ih = (const float*)d_in[3];
  const float* b_hh = (const float*)d_in[4];
  const float* fc_w = (const float*)d_in[5];
  const float* fc_b = (const float*)d_in[6];
  float* xp  = (float*)d_ws;         // B*T*H fp32 = 64 MB scratch
  float* out = (float*)d_out;

  xp_gemm<<<(BSZ * TSZ) / BM, 256, 0, stream>>>(x, W_ih, b_ih, b_hh, xp);
  rnn_scan<<<BSZ, 128, 0, stream>>>(xp, W_hh, fc_w, fc_b, out);
}

// Round 2
// 645.465 us; speedup vs baseline: 1.0258x; 1.0258x over previous
//
#include <hip/hip_runtime.h>
#include <cstdint>
#include <cstddef>

#define KIN 300
#define HIDDEN 128
#define BSZ 256
#define TSZ 512

typedef __attribute__((ext_vector_type(8))) short short8;
typedef __attribute__((ext_vector_type(4))) float f32x4;

__device__ __forceinline__ short f2bf(float f) {
  uint32_t u = __builtin_bit_cast(uint32_t, f);
  u = (u + 0x7FFFu + ((u >> 16) & 1u)) >> 16;
  return (short)u;
}
__device__ __forceinline__ float bf2f(short s) {
  uint32_t u = ((uint32_t)(uint16_t)s) << 16;
  return __builtin_bit_cast(float, u);
}
__device__ __forceinline__ uint32_t pack2bf(float a, float b) {
  return (uint32_t)(uint16_t)f2bf(a) | ((uint32_t)(uint16_t)f2bf(b) << 16);
}
__device__ __forceinline__ float tanhf_fast(float v) {
  const float e = __expf(-2.0f * fabsf(v));
  const float r = __fdividef(1.0f - e, 1.0f + e);
  return copysignf(r, v);
}
// Barrier that waits LDS ops but leaves global loads (vmcnt) in flight,
// so the xp register prefetch pipelines across steps.
__device__ __forceinline__ void barrier_lds() {
  asm volatile("s_waitcnt lgkmcnt(0)\n\ts_barrier" ::: "memory");
}

// ---------------- Phase 1: xp = x @ W_ih^T + (b_ih + b_hh)  (bf16 MFMA) ----
// M = B*T = 131072, K = 300 (pad 320), N = 128. 128x128 block tile,
// 4 waves in 2x2, each wave 64x64 via 4x4 grid of 16x16x32 MFMAs.
__global__ __launch_bounds__(256) void xp_gemm_mfma(
    const float* __restrict__ x, const float* __restrict__ Wih,
    const float* __restrict__ b_ih, const float* __restrict__ b_hh,
    float* __restrict__ xp) {
  // stride 40 shorts = 80 B: rows 16B-aligned, odd /16 quotient -> even banks
  __shared__ __align__(16) short As[128][40];
  __shared__ __align__(16) short Bs[128][40];
  const int tid = threadIdx.x;
  const int lane = tid & 63, w = tid >> 6;
  const int q = lane >> 4, c = lane & 15;
  const int mq = w & 1, nq = w >> 1;
  const int m0b = blockIdx.x * 128;

  f32x4 acc[4][4];
#pragma unroll
  for (int mt = 0; mt < 4; ++mt)
#pragma unroll
    for (int nt = 0; nt < 4; ++nt) acc[mt][nt] = (f32x4){0.f, 0.f, 0.f, 0.f};

  for (int kc = 0; kc < 10; ++kc) {
    const int k0 = kc * 32;
    // stage A (x tile) and B (W_ih rows) as bf16; zero-pad K beyond 299
#pragma unroll
    for (int p = 0; p < 4; ++p) {
      const int f = tid + 256 * p;
      const int row = f >> 3;
      const int off4 = (f & 7) << 2;
      const int k = k0 + off4;
      float4 va, vb;
      if (k + 3 < KIN) {
        va = *(const float4*)(x + (size_t)(m0b + row) * KIN + k);
        vb = *(const float4*)(Wih + (size_t)row * KIN + k);
      } else {
        va = make_float4(0.f, 0.f, 0.f, 0.f);
        vb = make_float4(0.f, 0.f, 0.f, 0.f);
      }
      uint2 pa, pb;
      pa.x = pack2bf(va.x, va.y);
      pa.y = pack2bf(va.z, va.w);
      pb.x = pack2bf(vb.x, vb.y);
      pb.y = pack2bf(vb.z, vb.w);
      *(uint2*)&As[row][off4] = pa;
      *(uint2*)&Bs[row][off4] = pb;
    }
    __syncthreads();

    short8 af[4], bf[4];
#pragma unroll
    for (int mt = 0; mt < 4; ++mt)
      af[mt] = *(const short8*)&As[mq * 64 + mt * 16 + c][q * 8];
#pragma unroll
    for (int nt = 0; nt < 4; ++nt)
      bf[nt] = *(const short8*)&Bs[nq * 64 + nt * 16 + c][q * 8];
#pragma unroll
    for (int mt = 0; mt < 4; ++mt)
#pragma unroll
      for (int nt = 0; nt < 4; ++nt)
        acc[mt][nt] = __builtin_amdgcn_mfma_f32_16x16x32_bf16(
            af[mt], bf[nt], acc[mt][nt], 0, 0, 0);
    __syncthreads();
  }

  // epilogue: + (b_ih + b_hh); C layout: row(M)=4q+r, col(N)=c
  float bias[4];
#pragma unroll
  for (int nt = 0; nt < 4; ++nt) {
    const int n = nq * 64 + nt * 16 + c;
    bias[nt] = b_ih[n] + b_hh[n];
  }
#pragma unroll
  for (int mt = 0; mt < 4; ++mt) {
    const int mrow = m0b + mq * 64 + mt * 16 + q * 4;
#pragma unroll
    for (int nt = 0; nt < 4; ++nt) {
      const int n = nq * 64 + nt * 16 + c;
#pragma unroll
      for (int r = 0; r < 4; ++r)
        xp[(size_t)(mrow + r) * HIDDEN + n] = acc[mt][nt][r] + bias[nt];
    }
  }
}

// ---------------- Phase 2: MFMA-batched scan + fused FC --------------------
// 16 blocks x 16 batch rows. Per step: P = W_hh (A, static VGPR frags) @
// H^T (B, from LDS). C layout (row=hidden=4q+r, col=batch=c) writes the next
// step's B-operand as one ds_write_b64 of 4 consecutive k. xp arrives via a
// depth-4 per-lane global->register prefetch ring (no LDS staging).
__global__ __launch_bounds__(256) void rnn_scan_mfma(
    const float* __restrict__ xp, const float* __restrict__ Whh,
    const float* __restrict__ fc_w, const float* __restrict__ fc_b,
    float* __restrict__ out) {
  // row stride 136 bf16 = 272 B (16B-aligned, /16 = 17 odd -> even bank use)
  __shared__ __align__(16) short ht[2][16][136];
  const int tid = threadIdx.x;
  const int lane = tid & 63, w = tid >> 6;
  const int q = lane >> 4, c = lane & 15;
  const int b0 = blockIdx.x * 16;

  // W_hh A-frags: wave w owns hidden-out rows [32w, 32w+32)
  short8 aw[2][4];
#pragma unroll
  for (int ti = 0; ti < 2; ++ti)
#pragma unroll
    for (int kc = 0; kc < 4; ++kc) {
      const float* src =
          Whh + (size_t)(w * 32 + ti * 16 + c) * HIDDEN + kc * 32 + q * 8;
      const float4 v0 = *(const float4*)(src);
      const float4 v1 = *(const float4*)(src + 4);
      short8 t;
      t[0] = f2bf(v0.x); t[1] = f2bf(v0.y); t[2] = f2bf(v0.z); t[3] = f2bf(v0.w);
      t[4] = f2bf(v1.x); t[5] = f2bf(v1.y); t[6] = f2bf(v1.z); t[7] = f2bf(v1.w);
      aw[ti][kc] = t;
    }

  // h0 = 0
  {
    uint32_t* z = (uint32_t*)&ht[0][0][0];
    for (int i = tid; i < (int)(sizeof(ht) / 8); i += 256) z[i] = 0;
  }

  // xp prefetch ring: lane (q,c) needs xp[b0+c][t][hb + 0..3] per tile
  const float* xpc = xp + (size_t)(b0 + c) * TSZ * HIDDEN;
  const int hb0 = w * 32 + q * 4;
  const int hb1 = hb0 + 16;
  float4 pf0[4], pf1[4];
#pragma unroll
  for (int d = 0; d < 4; ++d) {
    pf0[d] = *(const float4*)(xpc + (size_t)d * HIDDEN + hb0);
    pf1[d] = *(const float4*)(xpc + (size_t)d * HIDDEN + hb1);
  }
  __syncthreads();

#define SCAN_STEP(T, DOLOAD)                                                  \
  {                                                                           \
    const int slot = (T) & 3;                                                 \
    const int rb = (T) & 1;                                                   \
    const short8 bh0 = *(const short8*)&ht[rb][c][0 * 32 + q * 8];            \
    const short8 bh1 = *(const short8*)&ht[rb][c][1 * 32 + q * 8];            \
    const short8 bh2 = *(const short8*)&ht[rb][c][2 * 32 + q * 8];            \
    const short8 bh3 = *(const short8*)&ht[rb][c][3 * 32 + q * 8];            \
    f32x4 a0 = {pf0[slot].x, pf0[slot].y, pf0[slot].z, pf0[slot].w};          \
    f32x4 a1 = {pf1[slot].x, pf1[slot].y, pf1[slot].z, pf1[slot].w};          \
    if (DOLOAD) {                                                             \
      pf0[slot] = *(const float4*)(xpc + (size_t)((T) + 4) * HIDDEN + hb0);   \
      pf1[slot] = *(const float4*)(xpc + (size_t)((T) + 4) * HIDDEN + hb1);   \
    }                                                                         \
    a0 = __builtin_amdgcn_mfma_f32_16x16x32_bf16(aw[0][0], bh0, a0, 0, 0, 0); \
    a1 = __builtin_amdgcn_mfma_f32_16x16x32_bf16(aw[1][0], bh0, a1, 0, 0, 0); \
    a0 = __builtin_amdgcn_mfma_f32_16x16x32_bf16(aw[0][1], bh1, a0, 0, 0, 0); \
    a1 = __builtin_amdgcn_mfma_f32_16x16x32_bf16(aw[1][1], bh1, a1, 0, 0, 0); \
    a0 = __builtin_amdgcn_mfma_f32_16x16x32_bf16(aw[0][2], bh2, a0, 0, 0, 0); \
    a1 = __builtin_amdgcn_mfma_f32_16x16x32_bf16(aw[1][2], bh2, a1, 0, 0, 0); \
    a0 = __builtin_amdgcn_mfma_f32_16x16x32_bf16(aw[0][3], bh3, a0, 0, 0, 0); \
    a1 = __builtin_amdgcn_mfma_f32_16x16x32_bf16(aw[1][3], bh3, a1, 0, 0, 0); \
    uint2 w0, w1;                                                             \
    w0.x = pack2bf(tanhf_fast(a0[0]), tanhf_fast(a0[1]));                     \
    w0.y = pack2bf(tanhf_fast(a0[2]), tanhf_fast(a0[3]));                     \
    w1.x = pack2bf(tanhf_fast(a1[0]), tanhf_fast(a1[1]));                     \
    w1.y = pack2bf(tanhf_fast(a1[2]), tanhf_fast(a1[3]));                     \
    *(uint2*)&ht[rb ^ 1][c][hb0] = w0;                                        \
    *(uint2*)&ht[rb ^ 1][c][hb1] = w1;                                        \
    barrier_lds();                                                            \
  }

#pragma unroll 4
  for (int t = 0; t < TSZ - 4; ++t) SCAN_STEP(t, true)
  SCAN_STEP(TSZ - 4, false)
  SCAN_STEP(TSZ - 3, false)
  SCAN_STEP(TSZ - 2, false)
  SCAN_STEP(TSZ - 1, false)
#undef SCAN_STEP

  // h_last is in ht[0] (last step t=511 wrote rb^1 = 0). FC: 32 outputs/block.
  if (tid < 32) {
    const int bi = tid >> 1, cls = tid & 1;
    float s = fc_b[cls];
    const float* fw = fc_w + cls * HIDDEN;
#pragma unroll 8
    for (int k = 0; k < HIDDEN; k += 4) {
      s = fmaf(bf2f(ht[0][bi][k + 0]), fw[k + 0], s);
      s = fmaf(bf2f(ht[0][bi][k + 1]), fw[k + 1], s);
      s = fmaf(bf2f(ht[0][bi][k + 2]), fw[k + 2], s);
      s = fmaf(bf2f(ht[0][bi][k + 3]), fw[k + 3], s);
    }
    out[(b0 + bi) * 2 + cls] = s;
  }
}

extern "C" void kernel_launch(void* const* d_in, const int* in_sizes, int n_in,
                              void* d_out, int out_size, void* d_ws, size_t ws_size,
                              hipStream_t stream) {
  const float* x    = (const float*)d_in[0];
  const float* W_ih = (const float*)d_in[1];
  const float* W_hh = (const float*)d_in[2];
  const float* b_ih = (const float*)d_in[3];
  const float* b_hh = (const float*)d_in[4];
  const float* fc_w = (const float*)d_in[5];
  const float* fc_b = (const float*)d_in[6];
  float* xp  = (float*)d_ws;  // B*T*H fp32 = 64 MB scratch
  float* out = (float*)d_out;

  xp_gemm_mfma<<<(BSZ * TSZ) / 128, 256, 0, stream>>>(x, W_ih, b_ih, b_hh, xp);
  rnn_scan_mfma<<<BSZ / 16, 256, 0, stream>>>(xp, W_hh, fc_w, fc_b, out);
}

// Round 3
// 564.682 us; speedup vs baseline: 1.1726x; 1.1431x over previous
//
#include <hip/hip_runtime.h>
#include <cstdint>
#include <cstddef>

#define KIN 300
#define HIDDEN 128
#define BSZ 256
#define TSZ 512

typedef __attribute__((ext_vector_type(8))) short short8;
typedef __attribute__((ext_vector_type(4))) float f32x4;

__device__ __forceinline__ short f2bf(float f) {
  uint32_t u = __builtin_bit_cast(uint32_t, f);
  u = (u + 0x7FFFu + ((u >> 16) & 1u)) >> 16;
  return (short)u;
}
__device__ __forceinline__ float bf2f(short s) {
  uint32_t u = ((uint32_t)(uint16_t)s) << 16;
  return __builtin_bit_cast(float, u);
}
__device__ __forceinline__ uint32_t pack2bf(float a, float b) {
  return (uint32_t)(uint16_t)f2bf(a) | ((uint32_t)(uint16_t)f2bf(b) << 16);
}
__device__ __forceinline__ float tanhf_fast(float v) {
  const float e = __expf(-2.0f * fabsf(v));
  const float r = __fdividef(1.0f - e, 1.0f + e);
  return copysignf(r, v);
}
// Barrier that waits LDS ops but leaves global loads (vmcnt) in flight.
__device__ __forceinline__ void barrier_lds() {
  asm volatile("s_waitcnt lgkmcnt(0)\n\ts_barrier" ::: "memory");
}

// ---------------- Phase 1: xp = x @ W_ih^T + (b_ih + b_hh)  (bf16 MFMA) ----
// M=131072, K=300 (pad 320), N=128. 128x128 tile, 4 waves 2x2, double-
// buffered LDS: one barrier/iter, chunk k+1 global loads fly under MFMA(k).
__global__ __launch_bounds__(256, 2) void xp_gemm_mfma(
    const float* __restrict__ x, const float* __restrict__ Wih,
    const float* __restrict__ b_ih, const float* __restrict__ b_hh,
    float* __restrict__ xp) {
  __shared__ __align__(16) short As[2][128][40];  // 20.5 KB
  __shared__ __align__(16) short Bs[2][128][40];
  const int tid = threadIdx.x;
  const int lane = tid & 63, w = tid >> 6;
  const int q = lane >> 4, c = lane & 15;
  const int mq = w & 1, nq = w >> 1;
  const int m0b = blockIdx.x * 128;

  f32x4 acc[4][4];
#pragma unroll
  for (int mt = 0; mt < 4; ++mt)
#pragma unroll
    for (int nt = 0; nt < 4; ++nt) acc[mt][nt] = (f32x4){0.f, 0.f, 0.f, 0.f};

  // staging registers: 4 float4 per matrix per chunk
  float4 ra[4], rbv[4];
  const int s_row = tid >> 3;          // 0..31 (+32 per p)
  const int s_off = (tid & 7) << 2;    // {0,4,..,28}

#define ISSUE_LOADS(KC)                                                     \
  {                                                                         \
    _Pragma("unroll") for (int p = 0; p < 4; ++p) {                         \
      const int row = s_row + 32 * p;                                       \
      const int k = (KC) * 32 + s_off;                                      \
      if (k + 3 < KIN) {                                                    \
        ra[p]  = *(const float4*)(x + (size_t)(m0b + row) * KIN + k);       \
        rbv[p] = *(const float4*)(Wih + (size_t)row * KIN + k);             \
      } else {                                                              \
        ra[p] = make_float4(0.f, 0.f, 0.f, 0.f);                            \
        rbv[p] = make_float4(0.f, 0.f, 0.f, 0.f);                          \
      }                                                                     \
    }                                                                       \
  }

#define STORE_TILES(BUF)                                                    \
  {                                                                         \
    _Pragma("unroll") for (int p = 0; p < 4; ++p) {                         \
      const int row = s_row + 32 * p;                                       \
      uint2 pa, pb;                                                         \
      pa.x = pack2bf(ra[p].x, ra[p].y);  pa.y = pack2bf(ra[p].z, ra[p].w);  \
      pb.x = pack2bf(rbv[p].x, rbv[p].y); pb.y = pack2bf(rbv[p].z, rbv[p].w);\
      *(uint2*)&As[BUF][row][s_off] = pa;                                   \
      *(uint2*)&Bs[BUF][row][s_off] = pb;                                   \
    }                                                                       \
  }

  ISSUE_LOADS(0)
  for (int kc = 0; kc < 10; ++kc) {
    const int buf = kc & 1;
    STORE_TILES(buf)        // vmcnt waits happen here (loads from prev iter)
    __syncthreads();
    if (kc < 9) ISSUE_LOADS(kc + 1)   // in flight under frag reads + MFMA

    short8 af[4], bfr[4];
#pragma unroll
    for (int mt = 0; mt < 4; ++mt)
      af[mt] = *(const short8*)&As[buf][mq * 64 + mt * 16 + c][q * 8];
#pragma unroll
    for (int nt = 0; nt < 4; ++nt)
      bfr[nt] = *(const short8*)&Bs[buf][nq * 64 + nt * 16 + c][q * 8];
#pragma unroll
    for (int mt = 0; mt < 4; ++mt)
#pragma unroll
      for (int nt = 0; nt < 4; ++nt)
        acc[mt][nt] = __builtin_amdgcn_mfma_f32_16x16x32_bf16(
            af[mt], bfr[nt], acc[mt][nt], 0, 0, 0);
    // no second barrier: next iter writes the OTHER buffer; the next
    // iteration's barrier protects the buffer we just read.
  }
#undef ISSUE_LOADS
#undef STORE_TILES

  float bias[4];
#pragma unroll
  for (int nt = 0; nt < 4; ++nt) {
    const int n = nq * 64 + nt * 16 + c;
    bias[nt] = b_ih[n] + b_hh[n];
  }
#pragma unroll
  for (int mt = 0; mt < 4; ++mt) {
    const int mrow = m0b + mq * 64 + mt * 16 + q * 4;
#pragma unroll
    for (int nt = 0; nt < 4; ++nt) {
      const int n = nq * 64 + nt * 16 + c;
#pragma unroll
      for (int r = 0; r < 4; ++r)
        xp[(size_t)(mrow + r) * HIDDEN + n] = acc[mt][nt][r] + bias[nt];
    }
  }
}

// ---------------- Phase 2: MFMA-batched scan + fused FC --------------------
// 16 blocks x 16 batch rows. Depth-16 per-lane register prefetch ring for xp
// (prefetch distance ~16 steps >> HBM latency -> vmcnt waits are no-ops).
// MFMA chain split 2+2 with a vector add to shorten the dependent path.
__global__ __launch_bounds__(256, 1) void rnn_scan_mfma(
    const float* __restrict__ xp, const float* __restrict__ Whh,
    const float* __restrict__ fc_w, const float* __restrict__ fc_b,
    float* __restrict__ out) {
  __shared__ __align__(16) short ht[2][16][136];
  const int tid = threadIdx.x;
  const int lane = tid & 63, w = tid >> 6;
  const int q = lane >> 4, c = lane & 15;
  const int b0 = blockIdx.x * 16;

  // W_hh A-frags: wave w owns hidden-out rows [32w, 32w+32)
  short8 aw[2][4];
#pragma unroll
  for (int ti = 0; ti < 2; ++ti)
#pragma unroll
    for (int kc = 0; kc < 4; ++kc) {
      const float* src =
          Whh + (size_t)(w * 32 + ti * 16 + c) * HIDDEN + kc * 32 + q * 8;
      const float4 v0 = *(const float4*)(src);
      const float4 v1 = *(const float4*)(src + 4);
      short8 t;
      t[0] = f2bf(v0.x); t[1] = f2bf(v0.y); t[2] = f2bf(v0.z); t[3] = f2bf(v0.w);
      t[4] = f2bf(v1.x); t[5] = f2bf(v1.y); t[6] = f2bf(v1.z); t[7] = f2bf(v1.w);
      aw[ti][kc] = t;
    }

  // h0 = 0 (only ht[0] needs zeroing; ht[1] is written at t=0 before use)
  {
    uint32_t* z = (uint32_t*)&ht[0][0][0];
    for (int i = tid; i < 1088; i += 256) z[i] = 0;
  }

  const float* xpc = xp + (size_t)(b0 + c) * TSZ * HIDDEN;
  const int hb0 = w * 32 + q * 4;
  const int hb1 = hb0 + 16;
  float4 pf0[16], pf1[16];
#pragma unroll
  for (int d = 0; d < 16; ++d) {
    pf0[d] = *(const float4*)(xpc + (size_t)d * HIDDEN + hb0);
    pf1[d] = *(const float4*)(xpc + (size_t)d * HIDDEN + hb1);
  }
  __syncthreads();

  const f32x4 zero4 = {0.f, 0.f, 0.f, 0.f};
#pragma unroll 16
  for (int t = 0; t < TSZ; ++t) {
    const int slot = t & 15;
    const int rb = t & 1;
    const short8 bh0 = *(const short8*)&ht[rb][c][0 * 32 + q * 8];
    const short8 bh1 = *(const short8*)&ht[rb][c][1 * 32 + q * 8];
    const short8 bh2 = *(const short8*)&ht[rb][c][2 * 32 + q * 8];
    const short8 bh3 = *(const short8*)&ht[rb][c][3 * 32 + q * 8];
    f32x4 p0 = {pf0[slot].x, pf0[slot].y, pf0[slot].z, pf0[slot].w};
    f32x4 p1 = {pf1[slot].x, pf1[slot].y, pf1[slot].z, pf1[slot].w};
    if (t + 16 < TSZ) {
      pf0[slot] = *(const float4*)(xpc + (size_t)(t + 16) * HIDDEN + hb0);
      pf1[slot] = *(const float4*)(xpc + (size_t)(t + 16) * HIDDEN + hb1);
    }
    f32x4 q0 = zero4, q1 = zero4;
    p0 = __builtin_amdgcn_mfma_f32_16x16x32_bf16(aw[0][0], bh0, p0, 0, 0, 0);
    p1 = __builtin_amdgcn_mfma_f32_16x16x32_bf16(aw[1][0], bh0, p1, 0, 0, 0);
    q0 = __builtin_amdgcn_mfma_f32_16x16x32_bf16(aw[0][1], bh1, q0, 0, 0, 0);
    q1 = __builtin_amdgcn_mfma_f32_16x16x32_bf16(aw[1][1], bh1, q1, 0, 0, 0);
    p0 = __builtin_amdgcn_mfma_f32_16x16x32_bf16(aw[0][2], bh2, p0, 0, 0, 0);
    p1 = __builtin_amdgcn_mfma_f32_16x16x32_bf16(aw[1][2], bh2, p1, 0, 0, 0);
    q0 = __builtin_amdgcn_mfma_f32_16x16x32_bf16(aw[0][3], bh3, q0, 0, 0, 0);
    q1 = __builtin_amdgcn_mfma_f32_16x16x32_bf16(aw[1][3], bh3, q1, 0, 0, 0);
    const f32x4 a0 = p0 + q0;
    const f32x4 a1 = p1 + q1;
    uint2 w0, w1;
    w0.x = pack2bf(tanhf_fast(a0[0]), tanhf_fast(a0[1]));
    w0.y = pack2bf(tanhf_fast(a0[2]), tanhf_fast(a0[3]));
    w1.x = pack2bf(tanhf_fast(a1[0]), tanhf_fast(a1[1]));
    w1.y = pack2bf(tanhf_fast(a1[2]), tanhf_fast(a1[3]));
    *(uint2*)&ht[rb ^ 1][c][hb0] = w0;
    *(uint2*)&ht[rb ^ 1][c][hb1] = w1;
    barrier_lds();
  }

  // h_last is in ht[0] (t=511 wrote rb^1 = 0). FC: 32 outputs/block.
  if (tid < 32) {
    const int bi = tid >> 1, cls = tid & 1;
    float s = fc_b[cls];
    const float* fw = fc_w + cls * HIDDEN;
#pragma unroll 8
    for (int k = 0; k < HIDDEN; k += 4) {
      s = fmaf(bf2f(ht[0][bi][k + 0]), fw[k + 0], s);
      s = fmaf(bf2f(ht[0][bi][k + 1]), fw[k + 1], s);
      s = fmaf(bf2f(ht[0][bi][k + 2]), fw[k + 2], s);
      s = fmaf(bf2f(ht[0][bi][k + 3]), fw[k + 3], s);
    }
    out[(b0 + bi) * 2 + cls] = s;
  }
}

extern "C" void kernel_launch(void* const* d_in, const int* in_sizes, int n_in,
                              void* d_out, int out_size, void* d_ws, size_t ws_size,
                              hipStream_t stream) {
  const float* x    = (const float*)d_in[0];
  const float* W_ih = (const float*)d_in[1];
  const float* W_hh = (const float*)d_in[2];
  const float* b_ih = (const float*)d_in[3];
  const float* b_hh = (const float*)d_in[4];
  const float* fc_w = (const float*)d_in[5];
  const float* fc_b = (const float*)d_in[6];
  float* xp  = (float*)d_ws;  // B*T*H fp32 = 64 MB scratch
  float* out = (float*)d_out;

  xp_gemm_mfma<<<(BSZ * TSZ) / 128, 256, 0, stream>>>(x, W_ih, b_ih, b_hh, xp);
  rnn_scan_mfma<<<BSZ / 16, 256, 0, stream>>>(xp, W_hh, fc_w, fc_b, out);
}